// Round 11
// baseline (1135.216 us; speedup 1.0000x reference)
//
#include <hip/hip_runtime.h>
#include <math.h>

// Problem constants (match reference)
#define NU_ 500000
#define NI_ 200000
#define NN_ 700000            // NU + NI
#define D_  64
#define E_  2000000
#define B_  131072
#define TWO_E 4000000

typedef _Float16 half4 __attribute__((ext_vector_type(4)));  // 8 B
typedef _Float16 half8 __attribute__((ext_vector_type(8)));  // 16 B

// ---------------------------------------------------------------------------
// Degree histogram, one endpoint per thread (2E threads), no rank output.
__global__ __launch_bounds__(256) void deg_kernel(const int* __restrict__ eu,
                                                  const int* __restrict__ ei,
                                                  int* __restrict__ cnt) {
    int t = blockIdx.x * 256 + threadIdx.x;   // t < 2E
    int e = t >> 1;
    int side = t & 1;
    int node = side ? (ei[e] + NU_) : eu[e];
    atomicAdd(&cnt[node], 1);
}

__global__ __launch_bounds__(256) void inv_kernel(const int* __restrict__ cnt,
                                                  float* __restrict__ inv) {
    int v = blockIdx.x * 256 + threadIdx.x;
    if (v >= NN_) return;
    int d = cnt[v];
    inv[v] = (d > 0) ? (1.0f / sqrtf((float)d)) : 0.0f;
}

// ---------------------------------------------------------------------------
// Two-level exclusive scan (1024 elements per block, Hillis-Steele in LDS).
__global__ __launch_bounds__(1024) void scan_block(const int* __restrict__ in, int n,
                                                   int* __restrict__ out,
                                                   int* __restrict__ psum) {
    __shared__ int lds[1024];
    int g = blockIdx.x * 1024 + threadIdx.x;
    int v = (g < n) ? in[g] : 0;
    lds[threadIdx.x] = v;
    __syncthreads();
    for (int off = 1; off < 1024; off <<= 1) {
        int t = (threadIdx.x >= (unsigned)off) ? lds[threadIdx.x - off] : 0;
        __syncthreads();
        lds[threadIdx.x] += t;
        __syncthreads();
    }
    if (g < n) out[g] = lds[threadIdx.x] - v;     // exclusive
    if (threadIdx.x == 1023 && psum) psum[blockIdx.x] = lds[1023];
}

__global__ __launch_bounds__(256) void scan_add(int* __restrict__ rowptr,
                                                const int* __restrict__ poff) {
    int g = blockIdx.x * 256 + threadIdx.x;
    if (g < NN_) rowptr[g] += poff[g >> 10];
    if (g == 0) rowptr[NN_] = TWO_E;              // total is statically known
}

// ---------------------------------------------------------------------------
// CSR fill, cursor-based: slot = atomicAdd(cursor[node]) (cursor pre-seeded
// with rowptr), entry stored via atomicExch. BOTH atomics target L2-resident
// arrays (cursor 2.8 MB, adj 16 MB = 2 MB/XCD) — R8 vs R10 A/B showed the
// cache-side write merge requires L2 residency (112 MB buckets: 250 MB
// write-through; 16 MB compact: collapses).
__global__ __launch_bounds__(256) void fill_kernel(const int* __restrict__ eu,
                                                   const int* __restrict__ ei,
                                                   int* __restrict__ cursor,
                                                   int* __restrict__ adj) {
    int t = blockIdx.x * 256 + threadIdx.x;   // t < 2E
    int e = t >> 1;
    int side = t & 1;
    int su = eu[e];
    int sv = ei[e] + NU_;
    int node = side ? sv : su;
    int nbr  = side ? su : sv;
    int p = atomicAdd(&cursor[node], 1);
    atomicExch(&adj[p], nbr);
}

// ---------------------------------------------------------------------------
// Convert the concatenated [ue; ie] f32 embeddings to fp16 rows (128 B/row).
__global__ __launch_bounds__(256) void conv_kernel(const float* __restrict__ ue,
                                                   const float* __restrict__ ie,
                                                   half4* __restrict__ xh) {
    int t = blockIdx.x * 256 + threadIdx.x;
    int b = t >> 4;
    int q = t & 15;
    const float4* src = (b < NU_)
        ? ((const float4*)(ue + (size_t)b * D_) + q)
        : ((const float4*)(ie + (size_t)(b - NU_) * D_) + q);
    float4 a = *src;
    half4 h;
    h[0] = (_Float16)a.x; h[1] = (_Float16)a.y;
    h[2] = (_Float16)a.z; h[3] = (_Float16)a.w;
    xh[(size_t)b * 16 + q] = h;
}

// ---------------------------------------------------------------------------
// fp16 pull (R8's proven single-batch loop): lane = g*8+q; g = neighbor slot
// (8), q = feature octet (16 B). 8 rows in flight per wave per step.
// out[v][:] = fp16( inv[v] * sum_n inv[n] * x[n][:] ), accumulation in f32.
__global__ __launch_bounds__(256) void pull_kernel(const half8* __restrict__ xh,
                                                   const float* __restrict__ inv,
                                                   const int* __restrict__ rowptr,
                                                   const int* __restrict__ adj,
                                                   half8* __restrict__ out) {
    int t = blockIdx.x * 256 + threadIdx.x;
    int v = t >> 6;
    int lane = t & 63;
    int g = lane >> 3;        // neighbor slot (0..7)
    int q = lane & 7;         // feature octet (features 8q..8q+7)
    int beg = rowptr[v];
    int end = rowptr[v + 1];
    float acc[8] = {0.f, 0.f, 0.f, 0.f, 0.f, 0.f, 0.f, 0.f};
    for (int j = beg; j < end; j += 8) {
        int i = j + g;
        bool valid = i < end;
        int n = valid ? adj[i] : 0;
        float w = valid ? inv[n] : 0.0f;      // inv is 2.8MB, L2-resident
        half8 a = xh[(size_t)n * 8 + q];
#pragma unroll
        for (int k = 0; k < 8; ++k)
            acc[k] += w * (float)a[k];
    }
    // combine the 8 neighbor slots (g occupies lane bits 3..5)
#pragma unroll
    for (int k = 0; k < 8; ++k) {
        acc[k] += __shfl_xor(acc[k], 8);
        acc[k] += __shfl_xor(acc[k], 16);
        acc[k] += __shfl_xor(acc[k], 32);
    }
    if (g == 0) {
        float iv = inv[v];
        half8 o;
#pragma unroll
        for (int k = 0; k < 8; ++k) o[k] = (_Float16)(iv * acc[k]);
        out[(size_t)v * 8 + q] = o;
    }
}

// ---------------------------------------------------------------------------
// Per-node finalization: layer-3 pull (from x2) + redistribute to
// lane-per-feature. Returns
//   Zfinal[lane] = emb[lane](f32) + x1[node][lane] + x2[node][lane] + inv*pull3.
__device__ __forceinline__ float node_final(int node,
                                            const float* __restrict__ embrow,
                                            const _Float16* __restrict__ x1,
                                            const _Float16* __restrict__ x2,
                                            const float* __restrict__ inv,
                                            const int* __restrict__ rowptr,
                                            const int* __restrict__ adj,
                                            int lane, int g, int q) {
    int beg = rowptr[node];
    int end = rowptr[node + 1];
    float acc[8] = {0.f, 0.f, 0.f, 0.f, 0.f, 0.f, 0.f, 0.f};
    for (int j = beg; j < end; j += 8) {
        int i = j + g;
        bool valid = i < end;
        int n = valid ? adj[i] : 0;
        float w = valid ? inv[n] : 0.0f;
        half8 a = *(const half8*)(x2 + ((unsigned)n * 64u + (unsigned)q * 8u));
#pragma unroll
        for (int k = 0; k < 8; ++k)
            acc[k] += w * (float)a[k];
    }
#pragma unroll
    for (int k = 0; k < 8; ++k) {
        acc[k] += __shfl_xor(acc[k], 8);
        acc[k] += __shfl_xor(acc[k], 16);
        acc[k] += __shfl_xor(acc[k], 32);
    }
    // redistribute: lane wants feature `lane` = 8*(lane>>3) + (lane&7)
    float red = 0.0f;
#pragma unroll
    for (int k = 0; k < 8; ++k) {
        float tmp = __shfl(acc[k], lane >> 3);
        red = ((lane & 7) == k) ? tmp : red;
    }
    float e0 = embrow[lane];
    float l1 = (float)x1[(unsigned)node * 64u + (unsigned)lane];
    float l2 = (float)x2[(unsigned)node * 64u + (unsigned)lane];
    return e0 + l1 + l2 + inv[node] * red;
}

// ---------------------------------------------------------------------------
// Fully fused finalize + score: one wave per pair b. No Z buffers:
// Z = emb(f32 exact) + layer1(XAh) + layer2(XBh) + layer3(pulled here).
__global__ __launch_bounds__(256) void final_score_kernel(
        const float* __restrict__ ue,
        const float* __restrict__ ie,
        const _Float16* __restrict__ x1,      // layer-1 X (fp16)
        const _Float16* __restrict__ x2,      // layer-2 X (fp16)
        const float* __restrict__ inv,
        const int* __restrict__ rowptr,
        const int* __restrict__ adj,
        const int* __restrict__ users,
        const int* __restrict__ items,
        const float* __restrict__ fw,
        float* __restrict__ out) {
    int t = blockIdx.x * 256 + threadIdx.x;
    int b = t >> 6;
    int lane = t & 63;
    int g = lane >> 3;
    int q = lane & 7;

    int u  = users[b];
    int io = items[b];              // item index (0-based in ie)
    int it = io + NU_;              // item node id
    float zu = node_final(u,  ue + (size_t)u * D_,  x1, x2, inv, rowptr, adj, lane, g, q);
    float zi = node_final(it, ie + (size_t)io * D_, x1, x2, inv, rowptr, adj, lane, g, q);

    // score: s = sum_{f,gg} fw[f,gg] * dot(zu[f*16: ], zi[gg*16: ])
    int f = lane >> 4;
    float s = 0.0f;
#pragma unroll
    for (int gg = 0; gg < 4; ++gg) {
        float pi = __shfl(zi, (gg << 4) | (lane & 15));
        float p = zu * pi;
        p += __shfl_xor(p, 1);
        p += __shfl_xor(p, 2);
        p += __shfl_xor(p, 4);
        p += __shfl_xor(p, 8);
        s += fw[f * 4 + gg] * p;
    }
    s += __shfl_xor(s, 16);
    s += __shfl_xor(s, 32);
    if (lane == 0) out[b] = s * 0.0625f;  // (1/4)*(1/4) layer-mean scaling
}

// ---------------------------------------------------------------------------
extern "C" void kernel_launch(void* const* d_in, const int* in_sizes, int n_in,
                              void* d_out, int out_size, void* d_ws, size_t ws_size,
                              hipStream_t stream) {
    const float* ue    = (const float*)d_in[0];  // [NU, 64]
    const float* ie    = (const float*)d_in[1];  // [NI, 64]
    const float* fw    = (const float*)d_in[2];  // [4, 4]
    const int*   eu    = (const int*)d_in[3];    // [E]
    const int*   eitem = (const int*)d_in[4];    // [E]
    const int*   users = (const int*)d_in[5];    // [B]
    const int*   items = (const int*)d_in[6];    // [B]
    float* scores = (float*)d_out;               // [B]

    const size_t xh_bytes = (size_t)NN_ * D_ * 2;             // 89.6 MB (fp16)
    const int NB_SCAN = (NN_ + 1023) / 1024;                  // 684

    char* ws = (char*)d_ws;
    half8* X0h   = (half8*)ws;  ws += xh_bytes;   // layer-0; reused as layer-2 out
    half8* XAh   = (half8*)ws;  ws += xh_bytes;   // layer-1
    float* inv   = (float*)ws;  ws += (size_t)NN_ * 4;
    int*   cnt   = (int*)ws;    ws += (size_t)NN_ * 4;
    int*   rowptr= (int*)ws;    ws += (size_t)(NN_ + 1) * 4;
    int*   cursor= (int*)ws;    ws += (size_t)NN_ * 4;
    int*   adj   = (int*)ws;    ws += (size_t)TWO_E * 4;      // 16 MB compact
    int*   psum  = (int*)ws;    ws += (size_t)NB_SCAN * 4;
    int*   poff  = (int*)ws;    ws += (size_t)NB_SCAN * 4;
    half8* XBh   = X0h;         // ping-pong: X0h dead after layer-1 pull

    // --- CSR build: deg -> scan -> cursor fill (all atomics L2-resident) ---
    hipMemsetAsync(cnt, 0, (size_t)NN_ * 4, stream);
    deg_kernel<<<TWO_E / 256, 256, 0, stream>>>(eu, eitem, cnt);
    inv_kernel<<<(NN_ + 255) / 256, 256, 0, stream>>>(cnt, inv);
    scan_block<<<NB_SCAN, 1024, 0, stream>>>(cnt, NN_, rowptr, psum);
    scan_block<<<1, 1024, 0, stream>>>(psum, NB_SCAN, poff, (int*)nullptr);
    scan_add<<<(NN_ + 255) / 256, 256, 0, stream>>>(rowptr, poff);
    hipMemcpyAsync(cursor, rowptr, (size_t)NN_ * 4, hipMemcpyDeviceToDevice, stream);
    fill_kernel<<<TWO_E / 256, 256, 0, stream>>>(eu, eitem, cursor, adj);

    // --- fp16 conversion of layer-0 X ----------------------------------
    conv_kernel<<<(NN_ * 16) / 256, 256, 0, stream>>>(ue, ie, (half4*)X0h);

    // --- propagation ----------------------------------------------------
    pull_kernel<<<(NN_ * D_) / 256, 256, 0, stream>>>(X0h, inv, rowptr, adj, XAh);
    pull_kernel<<<(NN_ * D_) / 256, 256, 0, stream>>>(XAh, inv, rowptr, adj, XBh);

    // --- fused finalize (emb + l1 + l2 + l3-pull) + score ---------------
    final_score_kernel<<<(B_ * D_) / 256, 256, 0, stream>>>(
        ue, ie, (const _Float16*)XAh, (const _Float16*)XBh,
        inv, rowptr, adj, users, items, fw, scores);
}

// Round 12
// 917.886 us; speedup vs baseline: 1.2368x; 1.2368x over previous
//
#include <hip/hip_runtime.h>
#include <math.h>

// Problem constants (match reference)
#define NU_ 500000
#define NI_ 200000
#define NN_ 700000            // NU + NI
#define D_  64
#define E_  2000000
#define B_  131072
#define TWO_E 4000000

typedef _Float16 half4 __attribute__((ext_vector_type(4)));  // 8 B
typedef _Float16 half8 __attribute__((ext_vector_type(8)));  // 16 B

// ---------------------------------------------------------------------------
// Fused: degree histogram + rank assignment (2E endpoint-threads) AND fp16
// conversion of the layer-0 embeddings (NN*16 threads). The conv streaming
// work hides under the random-atomic latency (deg part: VALUBusy ~0.4%).
__global__ __launch_bounds__(256) void degrank_conv_kernel(
        const int* __restrict__ eu,
        const int* __restrict__ ei,
        int* __restrict__ cnt,
        int* __restrict__ rk,
        const float* __restrict__ ue,
        const float* __restrict__ ie,
        half4* __restrict__ xh) {
    int t = blockIdx.x * 256 + threadIdx.x;   // t < NN*16 (11.2M)
    if (t < TWO_E) {
        int e = t >> 1;
        int side = t & 1;
        int node = side ? (ei[e] + NU_) : eu[e];
        rk[t] = atomicAdd(&cnt[node], 1);     // rank within node's CSR row
    }
    // fp16 conversion: b = node, q = feature quad
    int b = t >> 4;
    int q = t & 15;
    const float4* src = (b < NU_)
        ? ((const float4*)(ue + (size_t)b * D_) + q)
        : ((const float4*)(ie + (size_t)(b - NU_) * D_) + q);
    float4 a = *src;
    half4 h;
    h[0] = (_Float16)a.x; h[1] = (_Float16)a.y;
    h[2] = (_Float16)a.z; h[3] = (_Float16)a.w;
    xh[(size_t)b * 16 + q] = h;
}

__global__ __launch_bounds__(256) void inv_kernel(const int* __restrict__ cnt,
                                                  float* __restrict__ inv) {
    int v = blockIdx.x * 256 + threadIdx.x;
    if (v >= NN_) return;
    int d = cnt[v];
    inv[v] = (d > 0) ? (1.0f / sqrtf((float)d)) : 0.0f;
}

// ---------------------------------------------------------------------------
// Two-level exclusive scan (1024 elements per block, Hillis-Steele in LDS).
__global__ __launch_bounds__(1024) void scan_block(const int* __restrict__ in, int n,
                                                   int* __restrict__ out,
                                                   int* __restrict__ psum) {
    __shared__ int lds[1024];
    int g = blockIdx.x * 1024 + threadIdx.x;
    int v = (g < n) ? in[g] : 0;
    lds[threadIdx.x] = v;
    __syncthreads();
    for (int off = 1; off < 1024; off <<= 1) {
        int t = (threadIdx.x >= (unsigned)off) ? lds[threadIdx.x - off] : 0;
        __syncthreads();
        lds[threadIdx.x] += t;
        __syncthreads();
    }
    if (g < n) out[g] = lds[threadIdx.x] - v;     // exclusive
    if (threadIdx.x == 1023 && psum) psum[blockIdx.x] = lds[1023];
}

__global__ __launch_bounds__(256) void scan_add(int* __restrict__ rowptr,
                                                const int* __restrict__ poff) {
    int g = blockIdx.x * 256 + threadIdx.x;
    if (g < NN_) rowptr[g] += poff[g >> 10];
    if (g == 0) rowptr[NN_] = TWO_E;              // total is statically known
}

// ---------------------------------------------------------------------------
// CSR fill: position = rowptr[node] + precomputed rank (plain loads), then a
// single UNCHAINED atomicExch. R8 vs R10/R11 A/B: the chained
// atomicAdd->atomicExch variant costs ~365 µs; this unchained form ~190 µs.
__global__ __launch_bounds__(256) void fill2_kernel(const int* __restrict__ eu,
                                                    const int* __restrict__ ei,
                                                    const int* __restrict__ rk,
                                                    const int* __restrict__ rowptr,
                                                    int* __restrict__ adj) {
    int t = blockIdx.x * 256 + threadIdx.x;   // t < 2E
    int e = t >> 1;
    int side = t & 1;
    int su = eu[e];
    int sv = ei[e] + NU_;
    int node = side ? sv : su;
    int nbr  = side ? su : sv;
    atomicExch(&adj[rowptr[node] + rk[t]], nbr);
}

// ---------------------------------------------------------------------------
// fp16 pull (R8's proven single-batch loop): lane = g*8+q; g = neighbor slot
// (8), q = feature octet (16 B). 8 rows in flight per wave per step.
// out[v][:] = fp16( inv[v] * sum_n inv[n] * x[n][:] ), accumulation in f32.
__global__ __launch_bounds__(256) void pull_kernel(const half8* __restrict__ xh,
                                                   const float* __restrict__ inv,
                                                   const int* __restrict__ rowptr,
                                                   const int* __restrict__ adj,
                                                   half8* __restrict__ out) {
    int t = blockIdx.x * 256 + threadIdx.x;
    int v = t >> 6;
    int lane = t & 63;
    int g = lane >> 3;        // neighbor slot (0..7)
    int q = lane & 7;         // feature octet (features 8q..8q+7)
    int beg = rowptr[v];
    int end = rowptr[v + 1];
    float acc[8] = {0.f, 0.f, 0.f, 0.f, 0.f, 0.f, 0.f, 0.f};
    for (int j = beg; j < end; j += 8) {
        int i = j + g;
        bool valid = i < end;
        int n = valid ? adj[i] : 0;
        float w = valid ? inv[n] : 0.0f;
        half8 a = xh[(size_t)n * 8 + q];
#pragma unroll
        for (int k = 0; k < 8; ++k)
            acc[k] += w * (float)a[k];
    }
    // combine the 8 neighbor slots (g occupies lane bits 3..5)
#pragma unroll
    for (int k = 0; k < 8; ++k) {
        acc[k] += __shfl_xor(acc[k], 8);
        acc[k] += __shfl_xor(acc[k], 16);
        acc[k] += __shfl_xor(acc[k], 32);
    }
    if (g == 0) {
        float iv = inv[v];
        half8 o;
#pragma unroll
        for (int k = 0; k < 8; ++k) o[k] = (_Float16)(iv * acc[k]);
        out[(size_t)v * 8 + q] = o;
    }
}

// ---------------------------------------------------------------------------
// Per-node finalization: layer-3 pull (from x2) + redistribute to
// lane-per-feature. Returns
//   Zfinal[lane] = emb[lane](f32) + x1[node][lane] + x2[node][lane] + inv*pull3.
__device__ __forceinline__ float node_final(int node,
                                            const float* __restrict__ embrow,
                                            const _Float16* __restrict__ x1,
                                            const _Float16* __restrict__ x2,
                                            const float* __restrict__ inv,
                                            const int* __restrict__ rowptr,
                                            const int* __restrict__ adj,
                                            int lane, int g, int q) {
    int beg = rowptr[node];
    int end = rowptr[node + 1];
    float acc[8] = {0.f, 0.f, 0.f, 0.f, 0.f, 0.f, 0.f, 0.f};
    for (int j = beg; j < end; j += 8) {
        int i = j + g;
        bool valid = i < end;
        int n = valid ? adj[i] : 0;
        float w = valid ? inv[n] : 0.0f;
        half8 a = *(const half8*)(x2 + ((unsigned)n * 64u + (unsigned)q * 8u));
#pragma unroll
        for (int k = 0; k < 8; ++k)
            acc[k] += w * (float)a[k];
    }
#pragma unroll
    for (int k = 0; k < 8; ++k) {
        acc[k] += __shfl_xor(acc[k], 8);
        acc[k] += __shfl_xor(acc[k], 16);
        acc[k] += __shfl_xor(acc[k], 32);
    }
    // redistribute: lane wants feature `lane` = 8*(lane>>3) + (lane&7)
    float red = 0.0f;
#pragma unroll
    for (int k = 0; k < 8; ++k) {
        float tmp = __shfl(acc[k], lane >> 3);
        red = ((lane & 7) == k) ? tmp : red;
    }
    float e0 = embrow[lane];
    float l1 = (float)x1[(unsigned)node * 64u + (unsigned)lane];
    float l2 = (float)x2[(unsigned)node * 64u + (unsigned)lane];
    return e0 + l1 + l2 + inv[node] * red;
}

// ---------------------------------------------------------------------------
// Fully fused finalize + score: one wave per pair b. No Z buffers:
// Z = emb(f32 exact) + layer1(XAh) + layer2(XBh) + layer3(pulled here).
__global__ __launch_bounds__(256) void final_score_kernel(
        const float* __restrict__ ue,
        const float* __restrict__ ie,
        const _Float16* __restrict__ x1,      // layer-1 X (fp16)
        const _Float16* __restrict__ x2,      // layer-2 X (fp16)
        const float* __restrict__ inv,
        const int* __restrict__ rowptr,
        const int* __restrict__ adj,
        const int* __restrict__ users,
        const int* __restrict__ items,
        const float* __restrict__ fw,
        float* __restrict__ out) {
    int t = blockIdx.x * 256 + threadIdx.x;
    int b = t >> 6;
    int lane = t & 63;
    int g = lane >> 3;
    int q = lane & 7;

    int u  = users[b];
    int io = items[b];              // item index (0-based in ie)
    int it = io + NU_;              // item node id
    float zu = node_final(u,  ue + (size_t)u * D_,  x1, x2, inv, rowptr, adj, lane, g, q);
    float zi = node_final(it, ie + (size_t)io * D_, x1, x2, inv, rowptr, adj, lane, g, q);

    // score: s = sum_{f,gg} fw[f,gg] * dot(zu[f*16: ], zi[gg*16: ])
    int f = lane >> 4;
    float s = 0.0f;
#pragma unroll
    for (int gg = 0; gg < 4; ++gg) {
        float pi = __shfl(zi, (gg << 4) | (lane & 15));
        float p = zu * pi;
        p += __shfl_xor(p, 1);
        p += __shfl_xor(p, 2);
        p += __shfl_xor(p, 4);
        p += __shfl_xor(p, 8);
        s += fw[f * 4 + gg] * p;
    }
    s += __shfl_xor(s, 16);
    s += __shfl_xor(s, 32);
    if (lane == 0) out[b] = s * 0.0625f;  // (1/4)*(1/4) layer-mean scaling
}

// ---------------------------------------------------------------------------
extern "C" void kernel_launch(void* const* d_in, const int* in_sizes, int n_in,
                              void* d_out, int out_size, void* d_ws, size_t ws_size,
                              hipStream_t stream) {
    const float* ue    = (const float*)d_in[0];  // [NU, 64]
    const float* ie    = (const float*)d_in[1];  // [NI, 64]
    const float* fw    = (const float*)d_in[2];  // [4, 4]
    const int*   eu    = (const int*)d_in[3];    // [E]
    const int*   eitem = (const int*)d_in[4];    // [E]
    const int*   users = (const int*)d_in[5];    // [B]
    const int*   items = (const int*)d_in[6];    // [B]
    float* scores = (float*)d_out;               // [B]

    const size_t xh_bytes = (size_t)NN_ * D_ * 2;             // 89.6 MB (fp16)
    const int NB_SCAN = (NN_ + 1023) / 1024;                  // 684

    char* ws = (char*)d_ws;
    half8* X0h   = (half8*)ws;  ws += xh_bytes;   // layer-0; reused as layer-2 out
    half8* XAh   = (half8*)ws;  ws += xh_bytes;   // layer-1
    float* inv   = (float*)ws;  ws += (size_t)NN_ * 4;
    int*   cnt   = (int*)ws;    ws += (size_t)NN_ * 4;
    int*   rowptr= (int*)ws;    ws += (size_t)(NN_ + 1) * 4;
    int*   adj   = (int*)ws;    ws += (size_t)TWO_E * 4;      // 16 MB compact
    int*   rk    = (int*)ws;    ws += (size_t)TWO_E * 4;      // 16 MB ranks
    int*   psum  = (int*)ws;    ws += (size_t)NB_SCAN * 4;
    int*   poff  = (int*)ws;    ws += (size_t)NB_SCAN * 4;
    half8* XBh   = X0h;         // ping-pong: X0h dead after layer-1 pull

    // --- CSR build (rank pass fused with fp16 conv) ---------------------
    hipMemsetAsync(cnt, 0, (size_t)NN_ * 4, stream);
    degrank_conv_kernel<<<(NN_ * 16) / 256, 256, 0, stream>>>(
        eu, eitem, cnt, rk, ue, ie, (half4*)X0h);
    inv_kernel<<<(NN_ + 255) / 256, 256, 0, stream>>>(cnt, inv);
    scan_block<<<NB_SCAN, 1024, 0, stream>>>(cnt, NN_, rowptr, psum);
    scan_block<<<1, 1024, 0, stream>>>(psum, NB_SCAN, poff, (int*)nullptr);
    scan_add<<<(NN_ + 255) / 256, 256, 0, stream>>>(rowptr, poff);
    fill2_kernel<<<TWO_E / 256, 256, 0, stream>>>(eu, eitem, rk, rowptr, adj);

    // --- propagation ----------------------------------------------------
    pull_kernel<<<(NN_ * D_) / 256, 256, 0, stream>>>(X0h, inv, rowptr, adj, XAh);
    pull_kernel<<<(NN_ * D_) / 256, 256, 0, stream>>>(XAh, inv, rowptr, adj, XBh);

    // --- fused finalize (emb + l1 + l2 + l3-pull) + score ---------------
    final_score_kernel<<<(B_ * D_) / 256, 256, 0, stream>>>(
        ue, ie, (const _Float16*)XAh, (const _Float16*)XBh,
        inv, rowptr, adj, users, items, fw, scores);
}

// Round 13
// 905.081 us; speedup vs baseline: 1.2543x; 1.0141x over previous
//
#include <hip/hip_runtime.h>
#include <math.h>

// Problem constants (match reference)
#define NU_ 500000
#define NI_ 200000
#define NN_ 700000            // NU + NI
#define D_  64
#define E_  2000000
#define B_  131072
#define TWO_E 4000000

typedef _Float16 half4 __attribute__((ext_vector_type(4)));  // 8 B
typedef _Float16 half8 __attribute__((ext_vector_type(8)));  // 16 B

// ---------------------------------------------------------------------------
// Fused: degree histogram + rank assignment (2E endpoint-threads) AND fp16
// conversion of the layer-0 embeddings (NN*16 threads). Conv streaming work
// hides under random-atomic latency (R12: fused kernel ≈ atomic pass alone).
__global__ __launch_bounds__(256) void degrank_conv_kernel(
        const int* __restrict__ eu,
        const int* __restrict__ ei,
        int* __restrict__ cnt,
        unsigned short* __restrict__ rk,
        const float* __restrict__ ue,
        const float* __restrict__ ie,
        half4* __restrict__ xh) {
    int t = blockIdx.x * 256 + threadIdx.x;   // t < NN*16 (11.2M)
    if (t < TWO_E) {
        int e = t >> 1;
        int side = t & 1;
        int node = side ? (ei[e] + NU_) : eu[e];
        rk[t] = (unsigned short)atomicAdd(&cnt[node], 1);  // deg max ~30 << 64K
    }
    // fp16 conversion: b = node, q = feature quad
    int b = t >> 4;
    int q = t & 15;
    const float4* src = (b < NU_)
        ? ((const float4*)(ue + (size_t)b * D_) + q)
        : ((const float4*)(ie + (size_t)(b - NU_) * D_) + q);
    float4 a = *src;
    half4 h;
    h[0] = (_Float16)a.x; h[1] = (_Float16)a.y;
    h[2] = (_Float16)a.z; h[3] = (_Float16)a.w;
    xh[(size_t)b * 16 + q] = h;
}

__global__ __launch_bounds__(256) void inv_kernel(const int* __restrict__ cnt,
                                                  float* __restrict__ inv) {
    int v = blockIdx.x * 256 + threadIdx.x;
    if (v >= NN_) return;
    int d = cnt[v];
    inv[v] = (d > 0) ? (1.0f / sqrtf((float)d)) : 0.0f;
}

// ---------------------------------------------------------------------------
// Two-level exclusive scan (1024 elements per block, Hillis-Steele in LDS).
__global__ __launch_bounds__(1024) void scan_block(const int* __restrict__ in, int n,
                                                   int* __restrict__ out,
                                                   int* __restrict__ psum) {
    __shared__ int lds[1024];
    int g = blockIdx.x * 1024 + threadIdx.x;
    int v = (g < n) ? in[g] : 0;
    lds[threadIdx.x] = v;
    __syncthreads();
    for (int off = 1; off < 1024; off <<= 1) {
        int t = (threadIdx.x >= (unsigned)off) ? lds[threadIdx.x - off] : 0;
        __syncthreads();
        lds[threadIdx.x] += t;
        __syncthreads();
    }
    if (g < n) out[g] = lds[threadIdx.x] - v;     // exclusive
    if (threadIdx.x == 1023 && psum) psum[blockIdx.x] = lds[1023];
}

__global__ __launch_bounds__(256) void scan_add(int* __restrict__ rowptr,
                                                const int* __restrict__ poff) {
    int g = blockIdx.x * 256 + threadIdx.x;
    if (g < NN_) rowptr[g] += poff[g >> 10];
    if (g == 0) rowptr[NN_] = TWO_E;              // total is statically known
}

// ---------------------------------------------------------------------------
// CSR fill: position = rowptr[node] + precomputed rank (plain loads), single
// UNCHAINED atomicExch (R8 vs R10/R11: chained atomic pairs cost ~365 µs,
// unchained ~190 µs).
__global__ __launch_bounds__(256) void fill2_kernel(const int* __restrict__ eu,
                                                    const int* __restrict__ ei,
                                                    const unsigned short* __restrict__ rk,
                                                    const int* __restrict__ rowptr,
                                                    int* __restrict__ adj) {
    int t = blockIdx.x * 256 + threadIdx.x;   // t < 2E
    int e = t >> 1;
    int side = t & 1;
    int su = eu[e];
    int sv = ei[e] + NU_;
    int node = side ? sv : su;
    int nbr  = side ? su : sv;
    atomicExch(&adj[rowptr[node] + (int)rk[t]], nbr);
}

// ---------------------------------------------------------------------------
// Layer-1 pull (inputs are RAW fp16 emb, so inv[n] gathers remain here).
// Output is PRE-SCALED: y1[v] = inv[v]^2 * sum_n inv[n]*x0[n]  (= inv[v]*x1[v]).
__global__ __launch_bounds__(256) void pull1_kernel(const half8* __restrict__ xh,
                                                    const float* __restrict__ inv,
                                                    const int* __restrict__ rowptr,
                                                    const int* __restrict__ adj,
                                                    half8* __restrict__ out) {
    int t = blockIdx.x * 256 + threadIdx.x;
    int v = t >> 6;
    int lane = t & 63;
    int g = lane >> 3;        // neighbor slot (0..7)
    int q = lane & 7;         // feature octet
    int beg = rowptr[v];
    int end = rowptr[v + 1];
    float acc[8] = {0.f, 0.f, 0.f, 0.f, 0.f, 0.f, 0.f, 0.f};
    for (int j = beg; j < end; j += 8) {
        int i = j + g;
        bool valid = i < end;
        int n = valid ? adj[i] : 0;
        float w = valid ? inv[n] : 0.0f;
        half8 a = xh[(size_t)n * 8 + q];
#pragma unroll
        for (int k = 0; k < 8; ++k)
            acc[k] += w * (float)a[k];
    }
#pragma unroll
    for (int k = 0; k < 8; ++k) {
        acc[k] += __shfl_xor(acc[k], 8);
        acc[k] += __shfl_xor(acc[k], 16);
        acc[k] += __shfl_xor(acc[k], 32);
    }
    if (g == 0) {
        float iv = inv[v];
        float iv2 = iv * iv;
        half8 o;
#pragma unroll
        for (int k = 0; k < 8; ++k) o[k] = (_Float16)(iv2 * acc[k]);
        out[(size_t)v * 8 + q] = o;
    }
}

// ---------------------------------------------------------------------------
// Layer-2 pull, FAST path: input y1 is pre-scaled, so the weighted sum
// collapses to an unweighted sum — NO inv[n] gather, NO weight fma. Masked
// slots read the dedicated zero row at index NN. y2[v] = inv[v]^2 * sum y1[n].
__global__ __launch_bounds__(256) void pull2_kernel(const half8* __restrict__ yh,
                                                    const float* __restrict__ inv,
                                                    const int* __restrict__ rowptr,
                                                    const int* __restrict__ adj,
                                                    half8* __restrict__ out) {
    int t = blockIdx.x * 256 + threadIdx.x;
    int v = t >> 6;
    int lane = t & 63;
    int g = lane >> 3;
    int q = lane & 7;
    int beg = rowptr[v];
    int end = rowptr[v + 1];
    float acc[8] = {0.f, 0.f, 0.f, 0.f, 0.f, 0.f, 0.f, 0.f};
    for (int j = beg; j < end; j += 8) {
        int i = j + g;
        int n = adj[i];                   // over-read lands in rk (in-ws, safe)
        n = (i < end) ? n : NN_;          // masked -> zero row
        half8 a = yh[(size_t)n * 8 + q];
#pragma unroll
        for (int k = 0; k < 8; ++k)
            acc[k] += (float)a[k];
    }
#pragma unroll
    for (int k = 0; k < 8; ++k) {
        acc[k] += __shfl_xor(acc[k], 8);
        acc[k] += __shfl_xor(acc[k], 16);
        acc[k] += __shfl_xor(acc[k], 32);
    }
    if (g == 0) {
        float iv = inv[v];
        float iv2 = iv * iv;
        half8 o;
#pragma unroll
        for (int k = 0; k < 8; ++k) o[k] = (_Float16)(iv2 * acc[k]);
        out[(size_t)v * 8 + q] = o;
    }
}

// ---------------------------------------------------------------------------
// Per-node finalization with pre-scaled layers:
//   layer-3 contribution = inv[node] * sum_n y2[n]   (unweighted sum)
//   x1+x2 at node = (y1[node]+y2[node]) * sqrt(deg[node])
//   Zfinal[lane] = emb + (y1+y2)*s + inv*sum(y2)
__device__ __forceinline__ float node_final(int node,
                                            const float* __restrict__ embrow,
                                            const _Float16* __restrict__ y1,
                                            const _Float16* __restrict__ y2,
                                            const float* __restrict__ inv,
                                            const int* __restrict__ cnt,
                                            const int* __restrict__ rowptr,
                                            const int* __restrict__ adj,
                                            int lane, int g, int q) {
    int beg = rowptr[node];
    int end = rowptr[node + 1];
    float acc[8] = {0.f, 0.f, 0.f, 0.f, 0.f, 0.f, 0.f, 0.f};
    for (int j = beg; j < end; j += 8) {
        int i = j + g;
        int n = adj[i];
        n = (i < end) ? n : NN_;          // masked -> zero row
        half8 a = *(const half8*)(y2 + ((unsigned)n * 64u + (unsigned)q * 8u));
#pragma unroll
        for (int k = 0; k < 8; ++k)
            acc[k] += (float)a[k];
    }
#pragma unroll
    for (int k = 0; k < 8; ++k) {
        acc[k] += __shfl_xor(acc[k], 8);
        acc[k] += __shfl_xor(acc[k], 16);
        acc[k] += __shfl_xor(acc[k], 32);
    }
    // redistribute: lane wants feature `lane` = 8*(lane>>3) + (lane&7)
    float red = 0.0f;
#pragma unroll
    for (int k = 0; k < 8; ++k) {
        float tmp = __shfl(acc[k], lane >> 3);
        red = ((lane & 7) == k) ? tmp : red;
    }
    float s  = sqrtf((float)cnt[node]);   // deg==0 -> 0, and y's are 0 too
    float l12 = ((float)y1[(unsigned)node * 64u + (unsigned)lane]
               + (float)y2[(unsigned)node * 64u + (unsigned)lane]) * s;
    return embrow[lane] + l12 + inv[node] * red;
}

// ---------------------------------------------------------------------------
// Fully fused finalize + score: one wave per pair b. No Z buffers.
__global__ __launch_bounds__(256) void final_score_kernel(
        const float* __restrict__ ue,
        const float* __restrict__ ie,
        const _Float16* __restrict__ y1,      // pre-scaled layer-1
        const _Float16* __restrict__ y2,      // pre-scaled layer-2
        const float* __restrict__ inv,
        const int* __restrict__ cnt,
        const int* __restrict__ rowptr,
        const int* __restrict__ adj,
        const int* __restrict__ users,
        const int* __restrict__ items,
        const float* __restrict__ fw,
        float* __restrict__ out) {
    int t = blockIdx.x * 256 + threadIdx.x;
    int b = t >> 6;
    int lane = t & 63;
    int g = lane >> 3;
    int q = lane & 7;

    int u  = users[b];
    int io = items[b];              // item index (0-based in ie)
    int it = io + NU_;              // item node id
    float zu = node_final(u,  ue + (size_t)u * D_,  y1, y2, inv, cnt, rowptr, adj, lane, g, q);
    float zi = node_final(it, ie + (size_t)io * D_, y1, y2, inv, cnt, rowptr, adj, lane, g, q);

    // score: s = sum_{f,gg} fw[f,gg] * dot(zu[f*16: ], zi[gg*16: ])
    int f = lane >> 4;
    float s = 0.0f;
#pragma unroll
    for (int gg = 0; gg < 4; ++gg) {
        float pi = __shfl(zi, (gg << 4) | (lane & 15));
        float p = zu * pi;
        p += __shfl_xor(p, 1);
        p += __shfl_xor(p, 2);
        p += __shfl_xor(p, 4);
        p += __shfl_xor(p, 8);
        s += fw[f * 4 + gg] * p;
    }
    s += __shfl_xor(s, 16);
    s += __shfl_xor(s, 32);
    if (lane == 0) out[b] = s * 0.0625f;  // (1/4)*(1/4) layer-mean scaling
}

// ---------------------------------------------------------------------------
extern "C" void kernel_launch(void* const* d_in, const int* in_sizes, int n_in,
                              void* d_out, int out_size, void* d_ws, size_t ws_size,
                              hipStream_t stream) {
    const float* ue    = (const float*)d_in[0];  // [NU, 64]
    const float* ie    = (const float*)d_in[1];  // [NI, 64]
    const float* fw    = (const float*)d_in[2];  // [4, 4]
    const int*   eu    = (const int*)d_in[3];    // [E]
    const int*   eitem = (const int*)d_in[4];    // [E]
    const int*   users = (const int*)d_in[5];    // [B]
    const int*   items = (const int*)d_in[6];    // [B]
    float* scores = (float*)d_out;               // [B]

    // (NN+1) rows: row NN is the dedicated zero row for masked gathers.
    const size_t xh_bytes = (size_t)(NN_ + 1) * D_ * 2;       // 89.6 MB + 128 B
    const int NB_SCAN = (NN_ + 1023) / 1024;                  // 684

    char* ws = (char*)d_ws;
    half8* X0h   = (half8*)ws;  ws += xh_bytes;   // raw fp16 emb; reused as y2 out
    half8* XAh   = (half8*)ws;  ws += xh_bytes;   // y1 (pre-scaled layer-1)
    float* inv   = (float*)ws;  ws += (size_t)NN_ * 4;
    int*   cnt   = (int*)ws;    ws += (size_t)NN_ * 4;
    int*   rowptr= (int*)ws;    ws += (size_t)(NN_ + 1) * 4;
    int*   adj   = (int*)ws;    ws += (size_t)TWO_E * 4;      // 16 MB compact
    unsigned short* rk = (unsigned short*)ws; ws += (size_t)TWO_E * 2;  // 8 MB
    int*   psum  = (int*)ws;    ws += (size_t)NB_SCAN * 4;
    int*   poff  = (int*)ws;    ws += (size_t)NB_SCAN * 4;
    half8* XBh   = X0h;         // ping-pong: X0h dead after pull-1

    // --- CSR build (rank pass fused with fp16 conv) ---------------------
    hipMemsetAsync(cnt, 0, (size_t)NN_ * 4, stream);
    // zero rows at index NN of both X buffers (128 B each, masked-gather target)
    hipMemsetAsync((char*)X0h + (size_t)NN_ * 128, 0, 128, stream);
    hipMemsetAsync((char*)XAh + (size_t)NN_ * 128, 0, 128, stream);
    degrank_conv_kernel<<<(NN_ * 16) / 256, 256, 0, stream>>>(
        eu, eitem, cnt, rk, ue, ie, (half4*)X0h);
    inv_kernel<<<(NN_ + 255) / 256, 256, 0, stream>>>(cnt, inv);
    scan_block<<<NB_SCAN, 1024, 0, stream>>>(cnt, NN_, rowptr, psum);
    scan_block<<<1, 1024, 0, stream>>>(psum, NB_SCAN, poff, (int*)nullptr);
    scan_add<<<(NN_ + 255) / 256, 256, 0, stream>>>(rowptr, poff);
    fill2_kernel<<<TWO_E / 256, 256, 0, stream>>>(eu, eitem, rk, rowptr, adj);

    // --- propagation: y1 = inv^2*Sum(inv*x0); y2 = inv^2*Sum(y1) --------
    pull1_kernel<<<(NN_ * D_) / 256, 256, 0, stream>>>(X0h, inv, rowptr, adj, XAh);
    pull2_kernel<<<(NN_ * D_) / 256, 256, 0, stream>>>(XAh, inv, rowptr, adj, XBh);

    // --- fused finalize (emb + (y1+y2)*sqrt(deg) + inv*Sum(y2)) + score --
    final_score_kernel<<<(B_ * D_) / 256, 256, 0, stream>>>(
        ue, ie, (const _Float16*)XAh, (const _Float16*)XBh,
        inv, cnt, rowptr, adj, users, items, fw, scores);
}

// Round 14
// 755.077 us; speedup vs baseline: 1.5034x; 1.1987x over previous
//
#include <hip/hip_runtime.h>
#include <math.h>

// Problem constants (match reference)
#define NU_ 500000
#define NI_ 200000
#define NN_ 700000            // NU + NI
#define D_  64
#define E_  2000000
#define B_  131072
#define TWO_E 4000000

#define SHIFT_ 10             // 1024 nodes per bucket
#define NBUCK_ 684            // ceil(700000 / 1024)
#define BCAP_  12288          // endpoints/bucket cap (item-bucket mean 10240, +20 sigma)
#define B1_TILE 16384         // endpoints per B1 block (256 thr x 64)

typedef _Float16 half4 __attribute__((ext_vector_type(4)));  // 8 B
typedef _Float16 half8 __attribute__((ext_vector_type(8)));  // 16 B

// ---------------------------------------------------------------------------
// B1a: coarse bucket histogram, LDS-aggregated (no random global atomics:
// 4M LDS adds + 684 coalesced-bin global adds per block).
__global__ __launch_bounds__(256) void bucket_hist_kernel(const int* __restrict__ eu,
                                                          const int* __restrict__ ei,
                                                          int* __restrict__ bucketCnt,
                                                          int* __restrict__ rowptr) {
    __shared__ int h[NBUCK_];
    for (int i = threadIdx.x; i < NBUCK_; i += 256) h[i] = 0;
    __syncthreads();
    size_t base = (size_t)blockIdx.x * B1_TILE;
    for (int k = 0; k < 64; ++k) {
        size_t idx = base + (size_t)k * 256 + threadIdx.x;
        if (idx < TWO_E) {
            int e = (int)(idx >> 1);
            int node = (idx & 1) ? (ei[e] + NU_) : eu[e];
            atomicAdd(&h[node >> SHIFT_], 1);
        }
    }
    __syncthreads();
    for (int i = threadIdx.x; i < NBUCK_; i += 256)
        if (h[i]) atomicAdd(&bucketCnt[i], h[i]);
    if (blockIdx.x == 0 && threadIdx.x == 0) rowptr[NN_] = TWO_E;
}

// ---------------------------------------------------------------------------
// Two-level exclusive scan helper (1024-elem blocks, Hillis-Steele in LDS).
__global__ __launch_bounds__(1024) void scan_block(const int* __restrict__ in, int n,
                                                   int* __restrict__ out,
                                                   int* __restrict__ psum) {
    __shared__ int lds[1024];
    int g = blockIdx.x * 1024 + threadIdx.x;
    int v = (g < n) ? in[g] : 0;
    lds[threadIdx.x] = v;
    __syncthreads();
    for (int off = 1; off < 1024; off <<= 1) {
        int t = (threadIdx.x >= (unsigned)off) ? lds[threadIdx.x - off] : 0;
        __syncthreads();
        lds[threadIdx.x] += t;
        __syncthreads();
    }
    if (g < n) out[g] = lds[threadIdx.x] - v;     // exclusive
    if (threadIdx.x == 1023 && psum) psum[blockIdx.x] = lds[1023];
}

// ---------------------------------------------------------------------------
// B1b: scatter (node,nbr) pairs into coarse bucket regions. Per-block LDS
// hist -> one global reservation per touched bucket -> LDS-ranked placement.
// Runs of ~24 pairs per bucket per block => ~190 B coalesced-ish writes.
__global__ __launch_bounds__(256) void bucket_scatter_kernel(const int* __restrict__ eu,
                                                             const int* __restrict__ ei,
                                                             int* __restrict__ cursor,
                                                             unsigned long long* __restrict__ pairs) {
    __shared__ int h[NBUCK_];
    __shared__ int basel[NBUCK_];
    for (int i = threadIdx.x; i < NBUCK_; i += 256) h[i] = 0;
    __syncthreads();
    size_t base = (size_t)blockIdx.x * B1_TILE;
    for (int k = 0; k < 64; ++k) {
        size_t idx = base + (size_t)k * 256 + threadIdx.x;
        if (idx < TWO_E) {
            int e = (int)(idx >> 1);
            int node = (idx & 1) ? (ei[e] + NU_) : eu[e];
            atomicAdd(&h[node >> SHIFT_], 1);
        }
    }
    __syncthreads();
    for (int i = threadIdx.x; i < NBUCK_; i += 256) {
        int c = h[i];
        basel[i] = c ? atomicAdd(&cursor[i], c) : 0;
    }
    __syncthreads();
    for (int i = threadIdx.x; i < NBUCK_; i += 256) h[i] = 0;   // reuse as ranks
    __syncthreads();
    for (int k = 0; k < 64; ++k) {
        size_t idx = base + (size_t)k * 256 + threadIdx.x;
        if (idx < TWO_E) {
            int e = (int)(idx >> 1);
            int side = (int)(idx & 1);
            int u = eu[e];
            int v = ei[e] + NU_;
            int node = side ? v : u;
            int nbr  = side ? u : v;
            int bk = node >> SHIFT_;
            int r = atomicAdd(&h[bk], 1);
            pairs[(size_t)basel[bk] + r] =
                ((unsigned long long)(unsigned)node << 32) | (unsigned)nbr;
        }
    }
}

// ---------------------------------------------------------------------------
// B2: per-bucket CSR build entirely in LDS; all global writes coalesced.
// Writes adj slice, rowptr slice, inv, sdeg. Zero global atomics.
__global__ __launch_bounds__(256) void csr_build_kernel(const unsigned long long* __restrict__ pairs,
                                                        const int* __restrict__ bucketBase,
                                                        int* __restrict__ rowptr,
                                                        int* __restrict__ adj,
                                                        float* __restrict__ inv,
                                                        float* __restrict__ sdeg) {
    __shared__ int cnt[1024];
    __shared__ int sA[1024];
    __shared__ int sB[1024];
    __shared__ int adjl[BCAP_];
    int b  = blockIdx.x;
    int lo = bucketBase[b];
    int hi = (b == NBUCK_ - 1) ? TWO_E : bucketBase[b + 1];
    int sz = hi - lo;
    if (sz > BCAP_) sz = BCAP_;               // defensive (P ~ 0)
    int node0 = b << SHIFT_;
    for (int i = threadIdx.x; i < 1024; i += 256) cnt[i] = 0;
    __syncthreads();
    for (int i = threadIdx.x; i < sz; i += 256) {
        int node = (int)(pairs[(size_t)lo + i] >> 32);
        atomicAdd(&cnt[node & 1023], 1);
    }
    __syncthreads();
    // inclusive scan of cnt (double-buffered Hillis-Steele, 256 thr / 1024 el)
    for (int i = threadIdx.x; i < 1024; i += 256) sA[i] = cnt[i];
    __syncthreads();
    int* cur = sA; int* nxt = sB;
    for (int off = 1; off < 1024; off <<= 1) {
        for (int i = threadIdx.x; i < 1024; i += 256)
            nxt[i] = cur[i] + (i >= off ? cur[i - off] : 0);
        __syncthreads();
        int* tmp = cur; cur = nxt; nxt = tmp;
    }
    // cur = inclusive; nxt becomes exclusive copy used as rank counters
    for (int i = threadIdx.x; i < 1024; i += 256) {
        int excl = cur[i] - cnt[i];
        nxt[i] = excl;
        int node = node0 + i;
        if (node < NN_) {
            rowptr[node] = lo + excl;
            int d = cnt[i];
            inv[node]  = d ? (1.0f / sqrtf((float)d)) : 0.0f;
            sdeg[node] = sqrtf((float)d);
        }
    }
    __syncthreads();
    for (int i = threadIdx.x; i < sz; i += 256) {
        unsigned long long p = pairs[(size_t)lo + i];
        int node = (int)(p >> 32);
        int nbr  = (int)(p & 0xffffffffu);
        int r = atomicAdd(&nxt[node & 1023], 1);
        if (r < BCAP_) adjl[r] = nbr;
    }
    __syncthreads();
    for (int i = threadIdx.x; i < sz; i += 256) adj[lo + i] = adjl[i];
}

// ---------------------------------------------------------------------------
// fp16 conversion of the concatenated [ue; ie] embeddings (128 B/row).
__global__ __launch_bounds__(256) void conv_kernel(const float* __restrict__ ue,
                                                   const float* __restrict__ ie,
                                                   half4* __restrict__ xh) {
    int t = blockIdx.x * 256 + threadIdx.x;
    int b = t >> 4;
    int q = t & 15;
    const float4* src = (b < NU_)
        ? ((const float4*)(ue + (size_t)b * D_) + q)
        : ((const float4*)(ie + (size_t)(b - NU_) * D_) + q);
    float4 a = *src;
    half4 h;
    h[0] = (_Float16)a.x; h[1] = (_Float16)a.y;
    h[2] = (_Float16)a.z; h[3] = (_Float16)a.w;
    xh[(size_t)b * 16 + q] = h;
}

// ---------------------------------------------------------------------------
// Layer-1 pull (weighted; raw fp16 emb input). Pre-scaled output:
// y1[v] = inv[v]^2 * sum_n inv[n]*x0[n].
__global__ __launch_bounds__(256) void pull1_kernel(const half8* __restrict__ xh,
                                                    const float* __restrict__ inv,
                                                    const int* __restrict__ rowptr,
                                                    const int* __restrict__ adj,
                                                    half8* __restrict__ out) {
    int t = blockIdx.x * 256 + threadIdx.x;
    int v = t >> 6;
    int lane = t & 63;
    int g = lane >> 3;
    int q = lane & 7;
    int beg = rowptr[v];
    int end = rowptr[v + 1];
    float acc[8] = {0.f, 0.f, 0.f, 0.f, 0.f, 0.f, 0.f, 0.f};
    for (int j = beg; j < end; j += 8) {
        int i = j + g;
        bool valid = i < end;
        int n = valid ? adj[i] : 0;
        float w = valid ? inv[n] : 0.0f;
        half8 a = xh[(size_t)n * 8 + q];
#pragma unroll
        for (int k = 0; k < 8; ++k)
            acc[k] += w * (float)a[k];
    }
#pragma unroll
    for (int k = 0; k < 8; ++k) {
        acc[k] += __shfl_xor(acc[k], 8);
        acc[k] += __shfl_xor(acc[k], 16);
        acc[k] += __shfl_xor(acc[k], 32);
    }
    if (g == 0) {
        float iv = inv[v];
        float iv2 = iv * iv;
        half8 o;
#pragma unroll
        for (int k = 0; k < 8; ++k) o[k] = (_Float16)(iv2 * acc[k]);
        out[(size_t)v * 8 + q] = o;
    }
}

// ---------------------------------------------------------------------------
// Layer-2 pull, unweighted (input pre-scaled). Masked slots read zero row NN.
__global__ __launch_bounds__(256) void pull2_kernel(const half8* __restrict__ yh,
                                                    const float* __restrict__ inv,
                                                    const int* __restrict__ rowptr,
                                                    const int* __restrict__ adj,
                                                    half8* __restrict__ out) {
    int t = blockIdx.x * 256 + threadIdx.x;
    int v = t >> 6;
    int lane = t & 63;
    int g = lane >> 3;
    int q = lane & 7;
    int beg = rowptr[v];
    int end = rowptr[v + 1];
    float acc[8] = {0.f, 0.f, 0.f, 0.f, 0.f, 0.f, 0.f, 0.f};
    for (int j = beg; j < end; j += 8) {
        int i = j + g;
        int n = adj[i];                   // over-read stays inside ws (pairs)
        n = (i < end) ? n : NN_;          // masked -> zero row
        half8 a = yh[(size_t)n * 8 + q];
#pragma unroll
        for (int k = 0; k < 8; ++k)
            acc[k] += (float)a[k];
    }
#pragma unroll
    for (int k = 0; k < 8; ++k) {
        acc[k] += __shfl_xor(acc[k], 8);
        acc[k] += __shfl_xor(acc[k], 16);
        acc[k] += __shfl_xor(acc[k], 32);
    }
    if (g == 0) {
        float iv = inv[v];
        float iv2 = iv * iv;
        half8 o;
#pragma unroll
        for (int k = 0; k < 8; ++k) o[k] = (_Float16)(iv2 * acc[k]);
        out[(size_t)v * 8 + q] = o;
    }
}

// ---------------------------------------------------------------------------
// Per-node finalization with pre-scaled layers:
//   Zfinal[lane] = emb + (y1+y2)*sdeg[node] + inv[node]*sum_n y2[n]
__device__ __forceinline__ float node_final(int node,
                                            const float* __restrict__ embrow,
                                            const _Float16* __restrict__ y1,
                                            const _Float16* __restrict__ y2,
                                            const float* __restrict__ inv,
                                            const float* __restrict__ sdeg,
                                            const int* __restrict__ rowptr,
                                            const int* __restrict__ adj,
                                            int lane, int g, int q) {
    int beg = rowptr[node];
    int end = rowptr[node + 1];
    float acc[8] = {0.f, 0.f, 0.f, 0.f, 0.f, 0.f, 0.f, 0.f};
    for (int j = beg; j < end; j += 8) {
        int i = j + g;
        int n = adj[i];
        n = (i < end) ? n : NN_;          // masked -> zero row
        half8 a = *(const half8*)(y2 + ((unsigned)n * 64u + (unsigned)q * 8u));
#pragma unroll
        for (int k = 0; k < 8; ++k)
            acc[k] += (float)a[k];
    }
#pragma unroll
    for (int k = 0; k < 8; ++k) {
        acc[k] += __shfl_xor(acc[k], 8);
        acc[k] += __shfl_xor(acc[k], 16);
        acc[k] += __shfl_xor(acc[k], 32);
    }
    // redistribute: lane wants feature `lane` = 8*(lane>>3) + (lane&7)
    float red = 0.0f;
#pragma unroll
    for (int k = 0; k < 8; ++k) {
        float tmp = __shfl(acc[k], lane >> 3);
        red = ((lane & 7) == k) ? tmp : red;
    }
    float s   = sdeg[node];
    float l12 = ((float)y1[(unsigned)node * 64u + (unsigned)lane]
               + (float)y2[(unsigned)node * 64u + (unsigned)lane]) * s;
    return embrow[lane] + l12 + inv[node] * red;
}

// ---------------------------------------------------------------------------
// Fully fused finalize + score: one wave per pair b.
__global__ __launch_bounds__(256) void final_score_kernel(
        const float* __restrict__ ue,
        const float* __restrict__ ie,
        const _Float16* __restrict__ y1,
        const _Float16* __restrict__ y2,
        const float* __restrict__ inv,
        const float* __restrict__ sdeg,
        const int* __restrict__ rowptr,
        const int* __restrict__ adj,
        const int* __restrict__ users,
        const int* __restrict__ items,
        const float* __restrict__ fw,
        float* __restrict__ out) {
    int t = blockIdx.x * 256 + threadIdx.x;
    int b = t >> 6;
    int lane = t & 63;
    int g = lane >> 3;
    int q = lane & 7;

    int u  = users[b];
    int io = items[b];
    int it = io + NU_;
    float zu = node_final(u,  ue + (size_t)u * D_,  y1, y2, inv, sdeg, rowptr, adj, lane, g, q);
    float zi = node_final(it, ie + (size_t)io * D_, y1, y2, inv, sdeg, rowptr, adj, lane, g, q);

    int f = lane >> 4;
    float s = 0.0f;
#pragma unroll
    for (int gg = 0; gg < 4; ++gg) {
        float pi = __shfl(zi, (gg << 4) | (lane & 15));
        float p = zu * pi;
        p += __shfl_xor(p, 1);
        p += __shfl_xor(p, 2);
        p += __shfl_xor(p, 4);
        p += __shfl_xor(p, 8);
        s += fw[f * 4 + gg] * p;
    }
    s += __shfl_xor(s, 16);
    s += __shfl_xor(s, 32);
    if (lane == 0) out[b] = s * 0.0625f;  // (1/4)*(1/4) layer-mean scaling
}

// ---------------------------------------------------------------------------
extern "C" void kernel_launch(void* const* d_in, const int* in_sizes, int n_in,
                              void* d_out, int out_size, void* d_ws, size_t ws_size,
                              hipStream_t stream) {
    const float* ue    = (const float*)d_in[0];  // [NU, 64]
    const float* ie    = (const float*)d_in[1];  // [NI, 64]
    const float* fw    = (const float*)d_in[2];  // [4, 4]
    const int*   eu    = (const int*)d_in[3];    // [E]
    const int*   eitem = (const int*)d_in[4];    // [E]
    const int*   users = (const int*)d_in[5];    // [B]
    const int*   items = (const int*)d_in[6];    // [B]
    float* scores = (float*)d_out;               // [B]

    // (NN+1) rows: row NN is the dedicated zero row for masked gathers.
    const size_t xh_bytes = (size_t)(NN_ + 1) * D_ * 2;       // 89.6 MB + 128 B

    char* ws = (char*)d_ws;
    half8* X0h  = (half8*)ws;  ws += xh_bytes;    // raw fp16 emb; reused as y2 out
    half8* XAh  = (half8*)ws;  ws += xh_bytes;    // y1
    unsigned long long* pairs = (unsigned long long*)ws; ws += (size_t)TWO_E * 8;  // 32 MB
    int*   adj  = (int*)ws;    ws += (size_t)TWO_E * 4;       // 16 MB
    int*   rowptr = (int*)ws;  ws += (size_t)(NN_ + 1) * 4;
    float* inv  = (float*)ws;  ws += (size_t)NN_ * 4;
    float* sdeg = (float*)ws;  ws += (size_t)NN_ * 4;
    int*   bucketCnt  = (int*)ws; ws += (size_t)NBUCK_ * 4;
    int*   bucketBase = (int*)ws; ws += (size_t)NBUCK_ * 4;
    int*   cursor     = (int*)ws; ws += (size_t)NBUCK_ * 4;
    half8* XBh  = X0h;          // ping-pong: X0h dead after pull1

    // --- atomic-free-ish CSR build (bucket sort) ------------------------
    hipMemsetAsync(bucketCnt, 0, (size_t)NBUCK_ * 4, stream);
    // zero rows at index NN of both X buffers (masked-gather target)
    hipMemsetAsync((char*)X0h + (size_t)NN_ * 128, 0, 128, stream);
    hipMemsetAsync((char*)XAh + (size_t)NN_ * 128, 0, 128, stream);
    const int NB1 = (TWO_E + B1_TILE - 1) / B1_TILE;          // 245
    bucket_hist_kernel<<<NB1, 256, 0, stream>>>(eu, eitem, bucketCnt, rowptr);
    scan_block<<<1, 1024, 0, stream>>>(bucketCnt, NBUCK_, bucketBase, (int*)nullptr);
    hipMemcpyAsync(cursor, bucketBase, (size_t)NBUCK_ * 4, hipMemcpyDeviceToDevice, stream);
    bucket_scatter_kernel<<<NB1, 256, 0, stream>>>(eu, eitem, cursor, pairs);
    csr_build_kernel<<<NBUCK_, 256, 0, stream>>>(pairs, bucketBase, rowptr, adj, inv, sdeg);

    // --- fp16 conversion of layer-0 X ----------------------------------
    conv_kernel<<<(NN_ * 16) / 256, 256, 0, stream>>>(ue, ie, (half4*)X0h);

    // --- propagation: y1 = inv^2*Sum(inv*x0); y2 = inv^2*Sum(y1) --------
    pull1_kernel<<<(NN_ * D_) / 256, 256, 0, stream>>>(X0h, inv, rowptr, adj, XAh);
    pull2_kernel<<<(NN_ * D_) / 256, 256, 0, stream>>>(XAh, inv, rowptr, adj, XBh);

    // --- fused finalize (emb + (y1+y2)*sdeg + inv*Sum(y2)) + score ------
    final_score_kernel<<<(B_ * D_) / 256, 256, 0, stream>>>(
        ue, ie, (const _Float16*)XAh, (const _Float16*)XBh,
        inv, sdeg, rowptr, adj, users, items, fw, scores);
}